// Round 1
// baseline (754.953 us; speedup 1.0000x reference)
//
#include <hip/hip_runtime.h>
#include <cstdint>
#include <cstddef>

#define N_INS    16384
#define INS_DIM  2048
#define N_CLS    81
#define BANK     10
#define LIST_CAP 3072
#define BK       64
#define AT_STRIDE 69     // 64 + pad (breaks power-of-2 LDS bank stride)
#define BT_STRIDE 100    // >= 96 so cg*6+5 stays in-row; even for float2 align

// ---------------------------------------------------------------------------
// Kernel 1: per-class mean over bank + ||mean||^2
// ---------------------------------------------------------------------------
__global__ __launch_bounds__(256)
void prep_kernel(const float* __restrict__ memory,
                 float* __restrict__ mean_out,   // [81][2048]
                 float* __restrict__ base_out)   // [81]
{
    const int c = blockIdx.x;
    const int t = threadIdx.x;
    double nrm = 0.0;
    #pragma unroll
    for (int rep = 0; rep < 2; ++rep) {
        const int d4 = (t + rep * 256) * 4;
        float sx = 0.f, sy = 0.f, sz = 0.f, sw = 0.f;
        #pragma unroll
        for (int b = 0; b < BANK; ++b) {
            const float4 v = *(const float4*)(memory + ((size_t)(c * BANK + b)) * INS_DIM + d4);
            sx += v.x; sy += v.y; sz += v.z; sw += v.w;
        }
        sx /= 10.0f; sy /= 10.0f; sz /= 10.0f; sw /= 10.0f;
        *(float4*)(mean_out + (size_t)c * INS_DIM + d4) = make_float4(sx, sy, sz, sw);
        nrm += (double)sx * sx + (double)sy * sy + (double)sz * sz + (double)sw * sw;
    }
    #pragma unroll
    for (int off = 32; off >= 1; off >>= 1) nrm += __shfl_xor(nrm, off, 64);
    __shared__ double sred[4];
    const int w = t >> 6, lane = t & 63;
    if (lane == 0) sred[w] = nrm;
    __syncthreads();
    if (t == 0) base_out[c] = (float)(sred[0] + sred[1] + sred[2] + sred[3]);
}

// ---------------------------------------------------------------------------
// Kernel 2: classification. Block = 64 instances x all 81 classes.
// Thread map: ig = t&15 (4 instances each), cg = t>>4 (6 classes each).
// ---------------------------------------------------------------------------
__global__ __launch_bounds__(256)
void classify_kernel(const float* __restrict__ instances,
                     const int*   __restrict__ labels,
                     const float* __restrict__ mean_in,   // [81][2048]
                     const float* __restrict__ base_in,   // [81]
                     float* __restrict__ cls_out,         // [16384]
                     float* __restrict__ acc_out)         // [1]
{
    __shared__ float  sAt[64 * AT_STRIDE];   // A[i][k]
    __shared__ float  sBt[BK * BT_STRIDE];   // B[k][c]
    __shared__ double redS[64 * 16];
    __shared__ int    redC[64 * 16];

    const int t  = threadIdx.x;
    const int ig = t & 15;
    const int cg = t >> 4;
    const int i0 = blockIdx.x * 64;

    double dacc[4][6];
    #pragma unroll
    for (int q = 0; q < 4; ++q)
        #pragma unroll
        for (int j = 0; j < 6; ++j) dacc[q][j] = 0.0;

    for (int k0 = 0; k0 < INS_DIM; k0 += BK) {
        // stage A tile: 64 instances x 64 k
        #pragma unroll
        for (int j = 0; j < 4; ++j) {
            const int u = t + 256 * j;
            const int r = u >> 4, f4 = (u & 15) * 4;
            const float4 v = *(const float4*)(instances + (size_t)(i0 + r) * INS_DIM + k0 + f4);
            float* dst = &sAt[r * AT_STRIDE + f4];
            dst[0] = v.x; dst[1] = v.y; dst[2] = v.z; dst[3] = v.w;
        }
        // stage B tile transposed: B[k][c]
        for (int u = t; u < 81 * 16; u += 256) {
            const int c = u >> 4, f4 = (u & 15) * 4;
            const float4 v = *(const float4*)(mean_in + (size_t)c * INS_DIM + k0 + f4);
            sBt[(f4 + 0) * BT_STRIDE + c] = v.x;
            sBt[(f4 + 1) * BT_STRIDE + c] = v.y;
            sBt[(f4 + 2) * BT_STRIDE + c] = v.z;
            sBt[(f4 + 3) * BT_STRIDE + c] = v.w;
        }
        // zero the pad columns 81..99 (keep garbage out of the FMAs)
        for (int u = t; u < 64 * 19; u += 256) {
            const int kk = u / 19, cc = 81 + (u % 19);
            sBt[kk * BT_STRIDE + cc] = 0.0f;
        }
        __syncthreads();

        float cacc[4][6];
        #pragma unroll
        for (int q = 0; q < 4; ++q)
            #pragma unroll
            for (int j = 0; j < 6; ++j) cacc[q][j] = 0.0f;

        for (int k = 0; k < BK; ++k) {
            float a[4];
            #pragma unroll
            for (int q = 0; q < 4; ++q) a[q] = sAt[(ig * 4 + q) * AT_STRIDE + k];
            const float* bp = &sBt[k * BT_STRIDE + cg * 6];
            const float2 b01 = *(const float2*)(bp);
            const float2 b23 = *(const float2*)(bp + 2);
            const float2 b45 = *(const float2*)(bp + 4);
            const float bv[6] = { b01.x, b01.y, b23.x, b23.y, b45.x, b45.y };
            #pragma unroll
            for (int q = 0; q < 4; ++q)
                #pragma unroll
                for (int j = 0; j < 6; ++j) cacc[q][j] += a[q] * bv[j];
        }
        #pragma unroll
        for (int q = 0; q < 4; ++q)
            #pragma unroll
            for (int j = 0; j < 6; ++j) dacc[q][j] += (double)cacc[q][j];
        __syncthreads();
    }

    // per-thread argmin over this thread's classes (ascending -> first-min)
    float bvals[6];
    #pragma unroll
    for (int j = 0; j < 6; ++j) {
        const int c = cg * 6 + j;
        bvals[j] = (c < N_CLS) ? base_in[c] : 0.0f;
    }
    #pragma unroll
    for (int q = 0; q < 4; ++q) {
        double best = 1e300; int bestc = 0x7fffffff;
        #pragma unroll
        for (int j = 0; j < 6; ++j) {
            const int c = cg * 6 + j;
            if (c < N_CLS) {
                const double sc = (double)bvals[j] - 2.0 * dacc[q][j];
                if (sc < best) { best = sc; bestc = c; }
            }
        }
        redS[(ig * 4 + q) * 16 + cg] = best;
        redC[(ig * 4 + q) * 16 + cg] = bestc;
    }
    __syncthreads();

    if (t < 64) {
        double best = redS[t * 16 + 0]; int bc = redC[t * 16 + 0];
        #pragma unroll
        for (int g = 1; g < 16; ++g) {
            const double v = redS[t * 16 + g];
            if (v < best) { best = v; bc = redC[t * 16 + g]; }
        }
        const int gi = i0 + t;
        cls_out[gi] = (float)bc;
        const bool ok = (bc == labels[gi]);
        const unsigned long long m = __ballot(ok ? 1 : 0);
        if (t == 0) atomicAdd(acc_out, (float)__popcll(m) * (1.0f / 16384.0f));
    }
}

// ---------------------------------------------------------------------------
// Kernel 3: sequential per-class memory update. Block = 1 class, 512 threads.
// Bank in registers: wave w owns slot w; waves 0,1 also own slots 8,9.
// ---------------------------------------------------------------------------
__global__ __launch_bounds__(512)
void update_kernel(const float* __restrict__ instances,
                   const int*   __restrict__ labels,
                   const float* __restrict__ memory,
                   const int*   __restrict__ memory_pos,
                   float* __restrict__ mem_out,   // [81][10][2048]
                   float* __restrict__ pos_out)   // [81]
{
    __shared__ int    s_list[LIST_CAP];
    __shared__ int    s_wcnt[8];
    __shared__ int    s_cnt;
    __shared__ double s_dist[2][BANK];

    const int c = blockIdx.x;
    const int t = threadIdx.x;
    const int w = t >> 6, lane = t & 63;

    // Phase 1: ordered list of instances with label == c (stable compaction)
    if (t == 0) s_cnt = 0;
    __syncthreads();
    for (int base = 0; base < N_INS; base += 512) {
        const int idx = base + t;
        const bool match = (labels[idx] == c);
        const unsigned long long mb = __ballot(match ? 1 : 0);
        if (lane == 0) s_wcnt[w] = (int)__popcll(mb);
        __syncthreads();
        int off = s_cnt;
        for (int ww = 0; ww < w; ++ww) off += s_wcnt[ww];
        off += (int)__popcll(mb & ((1ull << lane) - 1ull));
        if (match && off < LIST_CAP) s_list[off] = idx;
        __syncthreads();
        if (t == 0) {
            int tot = 0;
            for (int ww = 0; ww < 8; ++ww) tot += s_wcnt[ww];
            s_cnt = min(s_cnt + tot, LIST_CAP);
        }
        __syncthreads();
    }
    const int cnt = s_cnt;

    // Phase 2: load bank into registers
    const int s0 = w;
    const int s1 = (w < 2) ? (8 + w) : -1;
    float4 m0[8], m1[8];
    #pragma unroll
    for (int j = 0; j < 8; ++j)
        m0[j] = *(const float4*)(memory + ((size_t)(c * BANK + s0)) * INS_DIM + j * 256 + lane * 4);
    #pragma unroll
    for (int j = 0; j < 8; ++j) m1[j] = make_float4(0.f, 0.f, 0.f, 0.f);
    if (s1 >= 0) {
        #pragma unroll
        for (int j = 0; j < 8; ++j)
            m1[j] = *(const float4*)(memory + ((size_t)(c * BANK + s1)) * INS_DIM + j * 256 + lane * 4);
    }
    int p = memory_pos[c];

    // Phase 3: sequential scan with prefetch double-buffer
    float4 xa[8], xb[8];
    #pragma unroll
    for (int j = 0; j < 8; ++j) { xa[j] = make_float4(0,0,0,0); xb[j] = make_float4(0,0,0,0); }
    if (cnt > 0) {
        const float* xp = instances + (size_t)s_list[0] * INS_DIM;
        #pragma unroll
        for (int j = 0; j < 8; ++j) xa[j] = *(const float4*)(xp + j * 256 + lane * 4);
    }

    auto step = [&](float4 (&xc)[8], float4 (&xn)[8], const int ii) {
        // prefetch next instance (overlaps reduce + barrier below)
        const int nidx = s_list[(ii + 1 < cnt) ? (ii + 1) : ii];
        const float* np = instances + (size_t)nidx * INS_DIM;
        #pragma unroll
        for (int j = 0; j < 8; ++j) xn[j] = *(const float4*)(np + j * 256 + lane * 4);

        // squared distances for owned slots (f32 diff = exact ref op; f64 acc)
        double d0 = 0.0, d1 = 0.0;
        #pragma unroll
        for (int j = 0; j < 8; ++j) {
            const float ax = m0[j].x - xc[j].x, ay = m0[j].y - xc[j].y;
            const float az = m0[j].z - xc[j].z, aw = m0[j].w - xc[j].w;
            d0 = fma((double)ax, (double)ax, d0);
            d0 = fma((double)ay, (double)ay, d0);
            d0 = fma((double)az, (double)az, d0);
            d0 = fma((double)aw, (double)aw, d0);
        }
        if (s1 >= 0) {
            #pragma unroll
            for (int j = 0; j < 8; ++j) {
                const float ax = m1[j].x - xc[j].x, ay = m1[j].y - xc[j].y;
                const float az = m1[j].z - xc[j].z, aw = m1[j].w - xc[j].w;
                d1 = fma((double)ax, (double)ax, d1);
                d1 = fma((double)ay, (double)ay, d1);
                d1 = fma((double)az, (double)az, d1);
                d1 = fma((double)aw, (double)aw, d1);
            }
        }
        #pragma unroll
        for (int off = 32; off >= 1; off >>= 1) {
            d0 += __shfl_xor(d0, off, 64);
            d1 += __shfl_xor(d1, off, 64);
        }
        const int b = ii & 1;
        if (lane == 0) {
            s_dist[b][s0] = d0;
            if (s1 >= 0) s_dist[b][s1] = d1;
        }
        __syncthreads();   // the only barrier per step (dist array double-buffered)

        int widx;
        if (p < BANK) {
            widx = p;
        } else {
            double bestv = s_dist[b][0]; widx = 0;
            #pragma unroll
            for (int s = 1; s < BANK; ++s) {
                const double v = s_dist[b][s];
                if (v > bestv) { bestv = v; widx = s; }   // strict > : first-max
            }
        }
        if (widx == s0) {
            #pragma unroll
            for (int j = 0; j < 8; ++j) m0[j] = xc[j];
        }
        if (s1 >= 0 && widx == s1) {
            #pragma unroll
            for (int j = 0; j < 8; ++j) m1[j] = xc[j];
        }
        if (p < BANK) ++p;
    };

    int ii = 0;
    while (ii < cnt) {
        step(xa, xb, ii); ++ii;
        if (ii >= cnt) break;
        step(xb, xa, ii); ++ii;
    }

    // Phase 4: write final bank + pos
    #pragma unroll
    for (int j = 0; j < 8; ++j)
        *(float4*)(mem_out + ((size_t)(c * BANK + s0)) * INS_DIM + j * 256 + lane * 4) = m0[j];
    if (s1 >= 0) {
        #pragma unroll
        for (int j = 0; j < 8; ++j)
            *(float4*)(mem_out + ((size_t)(c * BANK + s1)) * INS_DIM + j * 256 + lane * 4) = m1[j];
    }
    if (t == 0) pos_out[c] = (float)p;
}

// ---------------------------------------------------------------------------
extern "C" void kernel_launch(void* const* d_in, const int* in_sizes, int n_in,
                              void* d_out, int out_size, void* d_ws, size_t ws_size,
                              hipStream_t stream)
{
    const float* instances = (const float*)d_in[0];
    const int*   labels    = (const int*)  d_in[1];
    const float* memory    = (const float*)d_in[2];
    const int*   mpos      = (const int*)  d_in[3];

    float* out      = (float*)d_out;
    float* cls_out  = out;                                   // [16384]
    float* acc_out  = out + N_INS;                           // [1]
    float* mem_out  = out + N_INS + 1;                       // [81*10*2048]
    float* pos_out  = mem_out + (size_t)N_CLS * BANK * INS_DIM; // [81]

    // scratch inside new_mem output region; update_kernel overwrites it last
    float* mean_scr = mem_out;                               // [81*2048]
    float* base_scr = mem_out + (size_t)N_CLS * INS_DIM;     // [81]

    hipMemsetAsync(acc_out, 0, sizeof(float), stream);
    hipLaunchKernelGGL(prep_kernel, dim3(N_CLS), dim3(256), 0, stream,
                       memory, mean_scr, base_scr);
    hipLaunchKernelGGL(classify_kernel, dim3(N_INS / 64), dim3(256), 0, stream,
                       instances, labels, mean_scr, base_scr, cls_out, acc_out);
    hipLaunchKernelGGL(update_kernel, dim3(N_CLS), dim3(512), 0, stream,
                       instances, labels, memory, mpos, mem_out, pos_out);
}